// Round 9
// baseline (644.581 us; speedup 1.0000x reference)
//
#include <hip/hip_runtime.h>
#include <hip/hip_bf16.h>
#include <cstddef>
#include <cstdint>

// B=8, L=512, H=768, DIN=1536, N=64, R=48, Kc=4. M = B*L = 4096.
#define DIN 1536
#define LSEQ 512

typedef __hip_bfloat16 bf16;
typedef __attribute__((ext_vector_type(8))) short short8x;
typedef __attribute__((ext_vector_type(4))) float f32x4;
typedef const __attribute__((address_space(1))) unsigned int* gp1;
typedef __attribute__((address_space(3))) unsigned int* lp3;

__device__ inline float readlane_f(float v, int l) {
  return __uint_as_float(__builtin_amdgcn_readlane(__float_as_uint(v), l));
}
__device__ inline void gload_lds(const bf16* g, unsigned short* l) {
  __builtin_amdgcn_global_load_lds((gp1)g, (lp3)l, 16, 0, 0);
}
__device__ inline void bsplit(float v, bf16& h, bf16& l) {
  h = __float2bfloat16(v);
  l = __float2bfloat16(v - __bfloat162float(h));
}
__device__ inline float softplusf(float t) {
  return fmaxf(t, 0.f) + log1pf(__expf(-fabsf(t)));
}
template<int CTRL>
__device__ inline float dpp_add(float v) {
  int t = __builtin_amdgcn_update_dpp(0, __float_as_int(v), CTRL, 0xf, 0xf, true);
  return v + __int_as_float(t);
}
// full-wave sum -> result valid in lane 63
__device__ inline float dpp_wave_sum(float p) {
  p = dpp_add<0x111>(p);  // row_shr:1
  p = dpp_add<0x112>(p);  // row_shr:2
  p = dpp_add<0x114>(p);  // row_shr:4
  p = dpp_add<0x118>(p);  // row_shr:8
  p = dpp_add<0x142>(p);  // row_bcast:15
  p = dpp_add<0x143>(p);  // row_bcast:31
  return p;
}

// ---------------------------------------------------------------------------
// bf16x3 MFMA GEMM. C = A*B fp32-accurate via hi/lo bf16 split (3 MFMA passes).
// A: [M][K] bf16 hi/lo (AMODE 1: concat of 3 segments of 768 along k).
// B: [N][K] bf16 hi/lo (transposed weights).
// EPI 1: C = acc + bias[col]
// EPI 4: softplus(acc+bias[col]) -> transposed [b][col][l]
// EPI 5: col<1536 -> C[row*ldc+col]; else acc -> C2 transposed [b][col-1536][l]
// EPI 6: C[row*192+col] = acc (fp32); col<64 -> Oh/Ol[row*64+col] = split(acc)
// ---------------------------------------------------------------------------
template<int TBM, int TBN, int WR, int WC, int AMODE, int EPI>
__global__ __launch_bounds__(WR*WC*64) void mgemm(
    const bf16* __restrict__ Ah0, const bf16* __restrict__ Al0,
    const bf16* __restrict__ Ah1, const bf16* __restrict__ Al1,
    const bf16* __restrict__ Ah2, const bf16* __restrict__ Al2,
    const bf16* __restrict__ Bh, const bf16* __restrict__ Bl,
    const float* __restrict__ bias,
    float* __restrict__ C, float* __restrict__ C2,
    bf16* __restrict__ Oh, bf16* __restrict__ Ol,
    int K, int lda, int ldc)
{
  constexpr int NW = WR * WC;
  constexpr int SM = TBM / WR, SN = TBN / WC;
  constexpr int T_M = SM / 16, T_N = SN / 16;
  __shared__ unsigned short sAh[TBM * 32], sAl[TBM * 32];
  __shared__ unsigned short sBh[TBN * 32], sBl[TBN * 32];
  const int tid = threadIdx.x;
  const int lane = tid & 63, wid = tid >> 6;
  const int bm = blockIdx.x * TBM, bn = blockIdx.y * TBN;
  const int wr = wid / WC, wc = wid % WC;

  const int stg_m = lane >> 2;
  const int stg_k = ((lane & 3) ^ ((lane >> 3) & 3)) * 8;
  const int fo = (lane & 15) * 64 + ((((lane >> 4) ^ ((lane >> 1) & 3)) & 3) * 16);

  f32x4 acc[T_M][T_N];
  #pragma unroll
  for (int i = 0; i < T_M; ++i)
    #pragma unroll
    for (int j = 0; j < T_N; ++j) acc[i][j] = (f32x4){0.f, 0.f, 0.f, 0.f};

  for (int k0 = 0; k0 < K; k0 += 32) {
    __syncthreads();
    const bf16* pAh; const bf16* pAl; int ka;
    if (AMODE == 1) {
      int seg = k0 / 768;
      pAh = (seg == 0) ? Ah0 : (seg == 1) ? Ah1 : Ah2;
      pAl = (seg == 0) ? Al0 : (seg == 1) ? Al1 : Al2;
      ka = k0 - seg * 768;
    } else { pAh = Ah0; pAl = Al0; ka = k0; }
    #pragma unroll
    for (int q = wid; q < TBM / 16; q += NW) {
      size_t go = (size_t)(bm + q * 16 + stg_m) * lda + ka + stg_k;
      gload_lds(pAh + go, &sAh[q * 512]);
      gload_lds(pAl + go, &sAl[q * 512]);
    }
    #pragma unroll
    for (int q = wid; q < TBN / 16; q += NW) {
      size_t go = (size_t)(bn + q * 16 + stg_m) * K + k0 + stg_k;
      gload_lds(Bh + go, &sBh[q * 512]);
      gload_lds(Bl + go, &sBl[q * 512]);
    }
    __syncthreads();

    short8x ah[T_M], al[T_M], bh[T_N], bl[T_N];
    #pragma unroll
    for (int mi = 0; mi < T_M; ++mi) {
      int off = (wr * SM + mi * 16) * 64 + fo;
      ah[mi] = *(const short8x*)((const char*)sAh + off);
      al[mi] = *(const short8x*)((const char*)sAl + off);
    }
    #pragma unroll
    for (int nj = 0; nj < T_N; ++nj) {
      int off = (wc * SN + nj * 16) * 64 + fo;
      bh[nj] = *(const short8x*)((const char*)sBh + off);
      bl[nj] = *(const short8x*)((const char*)sBl + off);
    }
    #pragma unroll
    for (int mi = 0; mi < T_M; ++mi)
      #pragma unroll
      for (int nj = 0; nj < T_N; ++nj) {
        acc[mi][nj] = __builtin_amdgcn_mfma_f32_16x16x32_bf16(ah[mi], bh[nj], acc[mi][nj], 0, 0, 0);
        acc[mi][nj] = __builtin_amdgcn_mfma_f32_16x16x32_bf16(ah[mi], bl[nj], acc[mi][nj], 0, 0, 0);
        acc[mi][nj] = __builtin_amdgcn_mfma_f32_16x16x32_bf16(al[mi], bh[nj], acc[mi][nj], 0, 0, 0);
      }
  }

  // epilogue — C/D layout: col = lane&15, row = (lane>>4)*4 + reg
  const int cl = lane & 15, qd = lane >> 4;
  const int colbase = bn + wc * SN;
  const int rowbase = bm + wr * SM;
  if (EPI == 1) {
    #pragma unroll
    for (int mi = 0; mi < T_M; ++mi) {
      int r0 = rowbase + mi * 16 + qd * 4;
      #pragma unroll
      for (int nj = 0; nj < T_N; ++nj) {
        int col = colbase + nj * 16 + cl;
        float bv = bias[col];
        #pragma unroll
        for (int rg = 0; rg < 4; ++rg)
          C[(size_t)(r0 + rg) * ldc + col] = acc[mi][nj][rg] + bv;
      }
    }
  } else if (EPI == 4) {
    #pragma unroll
    for (int mi = 0; mi < T_M; ++mi) {
      int m = rowbase + mi * 16 + qd * 4;
      int b = m >> 9, l = m & 511;
      #pragma unroll
      for (int nj = 0; nj < T_N; ++nj) {
        int col = colbase + nj * 16 + cl;
        float bv = bias[col];
        float4 v;
        v.x = softplusf(acc[mi][nj][0] + bv);
        v.y = softplusf(acc[mi][nj][1] + bv);
        v.z = softplusf(acc[mi][nj][2] + bv);
        v.w = softplusf(acc[mi][nj][3] + bv);
        *reinterpret_cast<float4*>(&C[((size_t)b * DIN + col) * LSEQ + l]) = v;
      }
    }
  } else if (EPI == 5) {
    if (bn < 1536) {
      #pragma unroll
      for (int mi = 0; mi < T_M; ++mi) {
        int r0 = rowbase + mi * 16 + qd * 4;
        #pragma unroll
        for (int nj = 0; nj < T_N; ++nj) {
          int col = colbase + nj * 16 + cl;
          #pragma unroll
          for (int rg = 0; rg < 4; ++rg)
            C[(size_t)(r0 + rg) * ldc + col] = acc[mi][nj][rg];
        }
      }
    } else {
      #pragma unroll
      for (int mi = 0; mi < T_M; ++mi) {
        int m = rowbase + mi * 16 + qd * 4;
        int b = m >> 9, l = m & 511;
        #pragma unroll
        for (int nj = 0; nj < T_N; ++nj) {
          int colz = colbase - 1536 + nj * 16 + cl;
          float4 v;
          v.x = acc[mi][nj][0]; v.y = acc[mi][nj][1];
          v.z = acc[mi][nj][2]; v.w = acc[mi][nj][3];
          *reinterpret_cast<float4*>(&C2[((size_t)b * DIN + colz) * LSEQ + l]) = v;
        }
      }
    }
  } else if (EPI == 6) {
    #pragma unroll
    for (int mi = 0; mi < T_M; ++mi) {
      int r0 = rowbase + mi * 16 + qd * 4;
      #pragma unroll
      for (int nj = 0; nj < T_N; ++nj) {
        int col = colbase + nj * 16 + cl;
        #pragma unroll
        for (int rg = 0; rg < 4; ++rg) {
          float v = acc[mi][nj][rg];
          C[(size_t)(r0 + rg) * 192 + col] = v;
          if (col < 64) {
            bf16 h, l;
            if (col < 48) bsplit(v, h, l);
            else { h = __float2bfloat16(0.f); l = h; }
            Oh[(size_t)(r0 + rg) * 64 + col] = h;
            Ol[(size_t)(r0 + rg) * 64 + col] = l;
          }
        }
      }
    }
  }
}

// ---------------------------------------------------------------------------
// Fused prep: modality hi/lo splits (blocks 0..36863) + all 4 weight
// transposes+splits (blocks 36864..37967).
__global__ __launch_bounds__(256) void prep_k(
    const float* __restrict__ s0, const float* __restrict__ s1,
    const float* __restrict__ s2, bf16* __restrict__ moddst,
    const float* __restrict__ pw, const float* __restrict__ ipw,
    const float* __restrict__ xpw, const float* __restrict__ dtw,
    bf16* pwTh, bf16* pwTl, bf16* ipTh, bf16* ipTl,
    bf16* xpTh, bf16* xpTl, bf16* dtTh, bf16* dtTl)
{
  __shared__ float T[64][65];
  const int tid = threadIdx.x;
  if (blockIdx.x < 36864) {
    const int per = 4096 * 768 / 256;
    int seg = blockIdx.x / per;
    int idx = (blockIdx.x - seg * per) * 256 + tid;
    const float* src = (seg == 0) ? s0 : (seg == 1) ? s1 : s2;
    bf16* hi = moddst + (size_t)seg * 2 * 4096 * 768;
    bf16* lo = hi + (size_t)4096 * 768;
    bf16 h, l; bsplit(src[idx], h, l);
    hi[idx] = h; lo[idx] = l;
    return;
  }
  const int id = blockIdx.x - 36864;
  const float* src; bf16 *hi, *lo; int P, Q, ld, Ppad, px, qx;
  if (id < 432)       { src = pw;  hi = pwTh; lo = pwTl; P = 2304; Q = 768;  ld = 768;  Ppad = 2304; px = id % 36;          qx = id / 36; }
  else if (id < 1008) { int i = id - 432;  src = ipw; hi = ipTh; lo = ipTl; P = 768;  Q = 3072; ld = 3072; Ppad = 768;  px = i % 12; qx = i / 12; }
  else if (id < 1080) { int i = id - 1008; src = xpw; hi = xpTh; lo = xpTl; P = 1536; Q = 176;  ld = 176;  Ppad = 1536; px = i % 24; qx = i / 24; }
  else                { int i = id - 1080; src = dtw; hi = dtTh; lo = dtTl; P = 48;   Q = 1536; ld = 1536; Ppad = 64;   px = 0;      qx = i; }
  const int p0 = px * 64, q0 = qx * 64;
  {
    int j = tid & 63, i0 = tid >> 6;
    for (int i = i0; i < 64; i += 4) {
      int p = p0 + i, q = q0 + j;
      T[i][j] = (p < P && q < Q) ? src[(size_t)p * ld + q] : 0.f;
    }
  }
  __syncthreads();
  {
    int ii = tid & 63, j0 = tid >> 6;
    for (int jj = j0; jj < 64; jj += 4) {
      bf16 h, l; bsplit(T[ii][jj], h, l);
      size_t o = (size_t)(q0 + jj) * Ppad + p0 + ii;
      hi[o] = h; lo[o] = l;
    }
  }
}

// ---------------------------------------------------------------------------
__device__ inline float block_sum256(float s, float* red) {
  #pragma unroll
  for (int o = 32; o > 0; o >>= 1) s += __shfl_xor(s, o, 64);
  int tid = threadIdx.x;
  __syncthreads();
  if ((tid & 63) == 0) red[tid >> 6] = s;
  __syncthreads();
  return red[0] + red[1] + red[2] + red[3];
}

__global__ __launch_bounds__(256) void ln2_k(
    const float* __restrict__ pre,
    const float* __restrict__ g1, const float* __restrict__ b1,
    const float* __restrict__ g2, const float* __restrict__ b2,
    float* __restrict__ fused, bf16* __restrict__ hAh, bf16* __restrict__ hAl)
{
  __shared__ float red[4];
  const int row = blockIdx.x;
  const int tid = threadIdx.x;
  const float* x = pre + (size_t)row * 768;
  float v0 = x[tid], v1 = x[tid + 256], v2 = x[tid + 512];

  float mu = block_sum256(v0 + v1 + v2, red) * (1.f / 768.f);
  float c0 = v0 - mu, c1 = v1 - mu, c2 = v2 - mu;
  float var = block_sum256(c0*c0 + c1*c1 + c2*c2, red) * (1.f / 768.f);
  float r = rsqrtf(var + 1e-5f);
  float f0 = c0 * r * g1[tid] + b1[tid];
  float f1 = c1 * r * g1[tid + 256] + b1[tid + 256];
  float f2 = c2 * r * g1[tid + 512] + b1[tid + 512];
  float* fo = fused + (size_t)row * 768;
  fo[tid] = f0; fo[tid + 256] = f1; fo[tid + 512] = f2;

  float mu2 = block_sum256(f0 + f1 + f2, red) * (1.f / 768.f);
  float d0 = f0 - mu2, d1 = f1 - mu2, d2 = f2 - mu2;
  float var2 = block_sum256(d0*d0 + d1*d1 + d2*d2, red) * (1.f / 768.f);
  float r2 = rsqrtf(var2 + 1e-5f);
  float h0 = d0 * r2 * g2[tid] + b2[tid];
  float h1 = d1 * r2 * g2[tid + 256] + b2[tid + 256];
  float h2 = d2 * r2 * g2[tid + 512] + b2[tid + 512];
  bf16 hh, hl;
  size_t o = (size_t)row * 768;
  bsplit(h0, hh, hl); hAh[o + tid] = hh; hAl[o + tid] = hl;
  bsplit(h1, hh, hl); hAh[o + tid + 256] = hh; hAl[o + tid + 256] = hl;
  bsplit(h2, hh, hl); hAh[o + tid + 512] = hh; hAl[o + tid + 512] = hl;
}

// Causal depthwise conv (K=4) + bias + silu.
// Outputs xct [B][DIN][L] fp32 (scan) AND xcA [row][DIN] bf16 hi/lo (x_proj A).
__global__ __launch_bounds__(256) void conv2x_k(
    const float* __restrict__ xbuf, const float* __restrict__ w,
    const float* __restrict__ cb, float* __restrict__ xct,
    bf16* __restrict__ xcAh, bf16* __restrict__ xcAl)
{
  __shared__ float Xs[67][65];
  __shared__ float Ys[64][65];
  const int tid = threadIdx.x;
  const int l0 = blockIdx.x * 64;
  const int d0 = blockIdx.y * 64;
  const int b  = blockIdx.z;
  for (int e = tid; e < 67 * 64; e += 256) {
    int r = e >> 6, dd = e & 63;
    int l = l0 - 3 + r;
    Xs[r][dd] = (l >= 0) ? xbuf[((size_t)b * 512 + l) * DIN + d0 + dd] : 0.f;
  }
  __syncthreads();
  {
    const int lane = tid & 63, grp = tid >> 6;
    #pragma unroll
    for (int i = 0; i < 16; ++i) {
      int dd = grp + i * 4;
      int d = d0 + dd;
      float acc = cb[d];
      #pragma unroll
      for (int k = 0; k < 4; ++k)
        acc = fmaf(Xs[lane + k][dd], w[d * 4 + k], acc);
      float v = acc / (1.f + __expf(-acc));
      xct[((size_t)b * DIN + d) * LSEQ + l0 + lane] = v;
      Ys[lane][dd] = v;
    }
  }
  __syncthreads();
  {
    const int dd = tid & 63, lg = tid >> 6;
    #pragma unroll
    for (int j = 0; j < 16; ++j) {
      int l = lg * 16 + j;
      bf16 h, lo; bsplit(Ys[l][dd], h, lo);
      size_t o = (size_t)(b * 512 + l0 + l) * DIN + d0 + dd;
      xcAh[o] = h; xcAl[o] = lo;
    }
  }
}

// Selective scan v7: 8 waves/block share one b; each wave handles TWO d
// channels (the BC read is shared, ILP doubles across the exp chain); lane = n.
// Scalars {dt,du,sz} staged per (wave,d,t) in padded LDS, read back per step
// as wave-uniform ds_read_b128 broadcasts -> zero readlanes in the hot loop.
// 768 blocks x 8 waves = 6144 waves = 24 waves/CU in a single batch.
__global__ __launch_bounds__(512) void scan7_k(
    const float* __restrict__ delta_t, const float* __restrict__ xct,
    const float* __restrict__ dbl, const float* __restrict__ zt,
    const float* __restrict__ A_log, const float* __restrict__ Dv,
    float* __restrict__ ysbar)
{
  __shared__ float BC[64][128];      // [t][2n+{0,1}] = {B,C}  32 KB (block-shared)
  __shared__ float DT[8][64][10];    // [wv][t][{dt0,du0,sz0,_,dt1,du1,sz1,_,pad2}] 20 KB
  const int tid = threadIdx.x;
  const int lane = tid & 63;
  const int wv = tid >> 6;           // 8 waves
  const int bid = blockIdx.x;        // 768 = 8 * 96
  const int b = bid / 96;
  const int g = bid - b * 96;
  const int d0 = g * 16 + wv * 2;    // this wave's two channels: d0, d0+1
  const int d1 = d0 + 1;
  const float Ad2 = -__expf(A_log[d0 * 64 + lane]) * 1.442695041f;  // same for all d
  const float Dd0 = Dv[d0], Dd1 = Dv[d1];
  const size_t strm0 = ((size_t)b * DIN + d0) * LSEQ;
  const size_t strm1 = ((size_t)b * DIN + d1) * LSEQ;
  float h0 = 0.f, h1 = 0.f;
  float a0 = 0.f, a1 = 0.f;          // Sum_t h[t,n]*C[t,n]*sz[t]  (lane = n)
  float us0 = 0.f, us1 = 0.f;        // Sum_t u[t]*sz[t]           (lane = t chunk)

  for (int l0 = 0; l0 < LSEQ; l0 += 64) {
    __syncthreads();
    #pragma unroll
    for (int i = 0; i < 8; ++i) {
      int t = wv * 8 + i;
      const float* src = dbl + (size_t)(b * LSEQ + l0 + t) * 192;
      float2 v; v.x = src[48 + lane]; v.y = src[112 + lane];
      *reinterpret_cast<float2*>(&BC[t][lane * 2]) = v;
    }
    {
      float dt0 = delta_t[strm0 + l0 + lane];
      float u0  = xct[strm0 + l0 + lane];
      float z0  = zt[strm0 + l0 + lane];
      float sz0 = z0 / (1.f + __expf(-z0));
      us0 += u0 * sz0;
      float4 s; s.x = dt0; s.y = dt0 * u0; s.z = sz0; s.w = 0.f;
      *reinterpret_cast<float4*>(&DT[wv][lane][0]) = s;
      float dt1 = delta_t[strm1 + l0 + lane];
      float u1  = xct[strm1 + l0 + lane];
      float z1  = zt[strm1 + l0 + lane];
      float sz1 = z1 / (1.f + __expf(-z1));
      us1 += u1 * sz1;
      float4 s1; s1.x = dt1; s1.y = dt1 * u1; s1.z = sz1; s1.w = 0.f;
      *reinterpret_cast<float4*>(&DT[wv][lane][4]) = s1;
    }
    __syncthreads();

    #pragma unroll
    for (int t = 0; t < 64; ++t) {
      float2 bc = *reinterpret_cast<const float2*>(&BC[t][lane * 2]);
      float4 s0 = *reinterpret_cast<const float4*>(&DT[wv][t][0]);   // broadcast
      float4 s1 = *reinterpret_cast<const float4*>(&DT[wv][t][4]);   // broadcast
      float e0 = exp2f(s0.x * Ad2);
      float e1 = exp2f(s1.x * Ad2);
      h0 = fmaf(e0, h0, s0.y * bc.x);
      h1 = fmaf(e1, h1, s1.y * bc.x);
      a0 = fmaf(h0, bc.y * s0.z, a0);
      a1 = fmaf(h1, bc.y * s1.z, a1);
    }
  }
  float tot0 = readlane_f(dpp_wave_sum(a0 + Dd0 * us0), 63);
  float tot1 = readlane_f(dpp_wave_sum(a1 + Dd1 * us1), 63);
  if (lane == 0) {
    ysbar[b * 1536 + d0] = tot0;
    ysbar[b * 1536 + d1] = tot1;
  }
}

// out[b][c] = (sum_l fused[b,l,c] + sum_d ysbar[b,d]*W[d,c]) / 512
__global__ __launch_bounds__(256) void final_k(
    const float* __restrict__ fused, const float* __restrict__ ysbar,
    const float* __restrict__ W, float* __restrict__ out)
{
  __shared__ float ys[1536];
  const int b = blockIdx.y;
  const int c = blockIdx.x * 256 + threadIdx.x;
  for (int i = threadIdx.x; i < 1536; i += 256) ys[i] = ysbar[b * 1536 + i];
  __syncthreads();
  float sf = 0.f;
  for (int l = 0; l < 512; ++l) sf += fused[(size_t)((b << 9) + l) * 768 + c];
  float dot = 0.f;
  for (int d = 0; d < 1536; ++d) dot = fmaf(ys[d], W[(size_t)d * 768 + c], dot);
  out[b * 768 + c] = (sf + dot) * (1.f / 512.f);
}

// ---------------------------------------------------------------------------
extern "C" void kernel_launch(void* const* d_in, const int* in_sizes, int n_in,
                              void* d_out, int out_size, void* d_ws, size_t ws_size,
                              hipStream_t stream)
{
  const float* text      = (const float*)d_in[0];
  const float* audio     = (const float*)d_in[1];
  const float* video     = (const float*)d_in[2];
  const float* proj_w    = (const float*)d_in[3];
  const float* proj_b    = (const float*)d_in[4];
  const float* proj_ln_g = (const float*)d_in[5];
  const float* proj_ln_b = (const float*)d_in[6];
  const float* blk_ln_g  = (const float*)d_in[7];
  const float* blk_ln_b  = (const float*)d_in[8];
  const float* in_proj_w = (const float*)d_in[9];
  const float* conv_w    = (const float*)d_in[10];
  const float* conv_b    = (const float*)d_in[11];
  const float* x_proj_w  = (const float*)d_in[12];
  const float* dt_proj_w = (const float*)d_in[13];
  const float* dt_proj_b = (const float*)d_in[14];
  const float* A_log     = (const float*)d_in[15];
  const float* Dv        = (const float*)d_in[16];
  const float* out_projw = (const float*)d_in[17];
  float* out = (float*)d_out;

  // ---- workspace arena ----
  char* p = (char*)d_ws;
  const size_t P768 = (size_t)4096 * 768 * 2;     // one bf16 [4096][768]
  char* S1 = p; p += 6 * P768;                    // modality splits -> hA -> xcA
  char* SW = p; p += 18087936;                    // weights
  char* S3 = p; p += (size_t)4096 * 768 * 4;      // pre
  char* S4 = p; p += (size_t)4096 * 768 * 4;      // fused
  char* S6 = p; p += (size_t)4096 * 1536 * 4;     // xbuf -> delta_t
  char* S7 = p; p += (size_t)4096 * 1536 * 4;     // zt
  char* S8 = p; p += (size_t)4096 * 1536 * 4;     // xct
  char* SD = p; p += (size_t)4096 * 64 * 4;       // dtA hi/lo
  char* S9 = p; p += (size_t)4096 * 192 * 4;      // dbl
  char* SY = p; p += 12288 * 4;                   // ysbar

  bf16* modspl = (bf16*)S1;
  bf16 *tAh = (bf16*)S1,              *tAl = (bf16*)(S1 + P768);
  bf16 *aAh = (bf16*)(S1 + 2 * P768), *aAl = (bf16*)(S1 + 3 * P768);
  bf16 *vAh = (bf16*)(S1 + 4 * P768), *vAl = (bf16*)(S1 + 5 * P768);
  bf16 *hAh = (bf16*)S1,              *hAl = (bf16*)(S1 + P768);
  bf16 *xcAh = (bf16*)S1,             *xcAl = (bf16*)(S1 + (size_t)4096 * 1536 * 2);
  bf16 *pwTh = (bf16*)SW,                    *pwTl = pwTh + (size_t)768 * 2304;
  bf16 *ipTh = pwTl + (size_t)768 * 2304,    *ipTl = ipTh + (size_t)3072 * 768;
  bf16 *xpTh = ipTl + (size_t)3072 * 768,    *xpTl = xpTh + (size_t)192 * 1536;
  bf16 *dtTh = xpTl + (size_t)192 * 1536,    *dtTl = dtTh + (size_t)1536 * 64;
  float* pre     = (float*)S3;
  float* fused   = (float*)S4;
  float* xbuf    = (float*)S6;  float* delta_t = (float*)S6;
  float* zt      = (float*)S7;
  float* xct     = (float*)S8;
  bf16 *dtAh = (bf16*)SD, *dtAl = (bf16*)(SD + (size_t)4096 * 64 * 2);
  float* dbl     = (float*)S9;
  float* ysbar   = (float*)SY;

  // 1) all prep (modality splits + weight transposes) in one launch
  prep_k<<<37968, 256, 0, stream>>>(text, audio, video, modspl,
                                    proj_w, in_proj_w, x_proj_w, dt_proj_w,
                                    pwTh, pwTl, ipTh, ipTl, xpTh, xpTl, dtTh, dtTl);
  // 2) pre = concat @ proj_w + proj_b
  mgemm<128, 64, 4, 2, 1, 1><<<dim3(32, 12), 512, 0, stream>>>(
      tAh, tAl, aAh, aAl, vAh, vAl, pwTh, pwTl, proj_b,
      pre, nullptr, nullptr, nullptr, 2304, 768, 768);
  // 3) fused = LN1(pre); hA = split(LN2(fused))
  ln2_k<<<4096, 256, 0, stream>>>(pre, proj_ln_g, proj_ln_b, blk_ln_g, blk_ln_b, fused, hAh, hAl);
  // 4) [x|z] = h @ in_proj_w: x -> xbuf [4096][1536], z -> zt [B][DIN][L]
  mgemm<128, 128, 2, 2, 0, 5><<<dim3(32, 24), 256, 0, stream>>>(
      hAh, hAl, nullptr, nullptr, nullptr, nullptr, ipTh, ipTl, nullptr,
      xbuf, zt, nullptr, nullptr, 768, 768, 1536);
  // 5) xct = silu(dwconv(x)+cb) transposed; xcA = split(xct) row-major
  conv2x_k<<<dim3(8, 24, 8), 256, 0, stream>>>(xbuf, conv_w, conv_b, xct, xcAh, xcAl);
  // 6) dbl = xconv @ x_proj_w [4096][192] fp32 + dtA hi/lo (cols<48, pad 64)
  mgemm<64, 64, 4, 2, 0, 6><<<dim3(64, 3), 512, 0, stream>>>(
      xcAh, xcAl, nullptr, nullptr, nullptr, nullptr, xpTh, xpTl, nullptr,
      dbl, nullptr, dtAh, dtAl, 1536, 1536, 192);
  // 7) delta_t = softplus(dt @ dt_proj_w + b) transposed [B][DIN][L]
  mgemm<128, 64, 4, 2, 0, 4><<<dim3(32, 24), 512, 0, stream>>>(
      dtAh, dtAl, nullptr, nullptr, nullptr, nullptr, dtTh, dtTl, dt_proj_b,
      delta_t, nullptr, nullptr, nullptr, 64, 64, 0);
  // 8) selective scan -> ysbar[b][d] = sum_l y
  scan7_k<<<768, 512, 0, stream>>>(delta_t, xct, dbl, zt, A_log, Dv, ysbar);
  // 9) out = (sum_l fused + ysbar @ out_proj_w) / 512
  final_k<<<dim3(3, 8), 256, 0, stream>>>(fused, ysbar, out_projw, out);
}

// Round 10
// 568.938 us; speedup vs baseline: 1.1330x; 1.1330x over previous
//
#include <hip/hip_runtime.h>
#include <hip/hip_bf16.h>
#include <cstddef>
#include <cstdint>

// B=8, L=512, H=768, DIN=1536, N=64, R=48, Kc=4. M = B*L = 4096.
#define DIN 1536
#define LSEQ 512

typedef __hip_bfloat16 bf16;
typedef __attribute__((ext_vector_type(8))) short short8x;
typedef __attribute__((ext_vector_type(4))) float f32x4;
typedef const __attribute__((address_space(1))) unsigned int* gp1;
typedef __attribute__((address_space(3))) unsigned int* lp3;

__device__ inline float readlane_f(float v, int l) {
  return __uint_as_float(__builtin_amdgcn_readlane(__float_as_uint(v), l));
}
__device__ inline void gload_lds(const bf16* g, unsigned short* l) {
  __builtin_amdgcn_global_load_lds((gp1)g, (lp3)l, 16, 0, 0);
}
__device__ inline void bsplit(float v, bf16& h, bf16& l) {
  h = __float2bfloat16(v);
  l = __float2bfloat16(v - __bfloat162float(h));
}
__device__ inline float softplusf(float t) {
  return fmaxf(t, 0.f) + log1pf(__expf(-fabsf(t)));
}
template<int CTRL>
__device__ inline float dpp_add(float v) {
  int t = __builtin_amdgcn_update_dpp(0, __float_as_int(v), CTRL, 0xf, 0xf, true);
  return v + __int_as_float(t);
}
// full-wave sum -> result valid in lane 63
__device__ inline float dpp_wave_sum(float p) {
  p = dpp_add<0x111>(p);  // row_shr:1
  p = dpp_add<0x112>(p);  // row_shr:2
  p = dpp_add<0x114>(p);  // row_shr:4
  p = dpp_add<0x118>(p);  // row_shr:8
  p = dpp_add<0x142>(p);  // row_bcast:15
  p = dpp_add<0x143>(p);  // row_bcast:31
  return p;
}

// ---------------------------------------------------------------------------
// bf16x3 MFMA GEMM. C = A*B fp32-accurate via hi/lo bf16 split (3 MFMA passes).
// A: [M][K] bf16 hi/lo (AMODE 1: concat of 3 segments of 768 along k).
// B: [N][K] bf16 hi/lo (transposed weights).
// EPI 1: C = acc + bias[col]
// EPI 4: softplus(acc+bias[col]) -> transposed [b][col][l]
// EPI 5: col<1536 -> C[row*ldc+col]; else acc -> C2 transposed [b][col-1536][l]
// EPI 6: C[row*192+col] = acc (fp32); col<64 -> Oh/Ol[row*64+col] = split(acc)
// ---------------------------------------------------------------------------
template<int TBM, int TBN, int WR, int WC, int AMODE, int EPI>
__global__ __launch_bounds__(WR*WC*64) void mgemm(
    const bf16* __restrict__ Ah0, const bf16* __restrict__ Al0,
    const bf16* __restrict__ Ah1, const bf16* __restrict__ Al1,
    const bf16* __restrict__ Ah2, const bf16* __restrict__ Al2,
    const bf16* __restrict__ Bh, const bf16* __restrict__ Bl,
    const float* __restrict__ bias,
    float* __restrict__ C, float* __restrict__ C2,
    bf16* __restrict__ Oh, bf16* __restrict__ Ol,
    int K, int lda, int ldc)
{
  constexpr int NW = WR * WC;
  constexpr int SM = TBM / WR, SN = TBN / WC;
  constexpr int T_M = SM / 16, T_N = SN / 16;
  __shared__ unsigned short sAh[TBM * 32], sAl[TBM * 32];
  __shared__ unsigned short sBh[TBN * 32], sBl[TBN * 32];
  const int tid = threadIdx.x;
  const int lane = tid & 63, wid = tid >> 6;
  const int bm = blockIdx.x * TBM, bn = blockIdx.y * TBN;
  const int wr = wid / WC, wc = wid % WC;

  const int stg_m = lane >> 2;
  const int stg_k = ((lane & 3) ^ ((lane >> 3) & 3)) * 8;
  const int fo = (lane & 15) * 64 + ((((lane >> 4) ^ ((lane >> 1) & 3)) & 3) * 16);

  f32x4 acc[T_M][T_N];
  #pragma unroll
  for (int i = 0; i < T_M; ++i)
    #pragma unroll
    for (int j = 0; j < T_N; ++j) acc[i][j] = (f32x4){0.f, 0.f, 0.f, 0.f};

  for (int k0 = 0; k0 < K; k0 += 32) {
    __syncthreads();
    const bf16* pAh; const bf16* pAl; int ka;
    if (AMODE == 1) {
      int seg = k0 / 768;
      pAh = (seg == 0) ? Ah0 : (seg == 1) ? Ah1 : Ah2;
      pAl = (seg == 0) ? Al0 : (seg == 1) ? Al1 : Al2;
      ka = k0 - seg * 768;
    } else { pAh = Ah0; pAl = Al0; ka = k0; }
    #pragma unroll
    for (int q = wid; q < TBM / 16; q += NW) {
      size_t go = (size_t)(bm + q * 16 + stg_m) * lda + ka + stg_k;
      gload_lds(pAh + go, &sAh[q * 512]);
      gload_lds(pAl + go, &sAl[q * 512]);
    }
    #pragma unroll
    for (int q = wid; q < TBN / 16; q += NW) {
      size_t go = (size_t)(bn + q * 16 + stg_m) * K + k0 + stg_k;
      gload_lds(Bh + go, &sBh[q * 512]);
      gload_lds(Bl + go, &sBl[q * 512]);
    }
    __syncthreads();

    short8x ah[T_M], al[T_M], bh[T_N], bl[T_N];
    #pragma unroll
    for (int mi = 0; mi < T_M; ++mi) {
      int off = (wr * SM + mi * 16) * 64 + fo;
      ah[mi] = *(const short8x*)((const char*)sAh + off);
      al[mi] = *(const short8x*)((const char*)sAl + off);
    }
    #pragma unroll
    for (int nj = 0; nj < T_N; ++nj) {
      int off = (wc * SN + nj * 16) * 64 + fo;
      bh[nj] = *(const short8x*)((const char*)sBh + off);
      bl[nj] = *(const short8x*)((const char*)sBl + off);
    }
    #pragma unroll
    for (int mi = 0; mi < T_M; ++mi)
      #pragma unroll
      for (int nj = 0; nj < T_N; ++nj) {
        acc[mi][nj] = __builtin_amdgcn_mfma_f32_16x16x32_bf16(ah[mi], bh[nj], acc[mi][nj], 0, 0, 0);
        acc[mi][nj] = __builtin_amdgcn_mfma_f32_16x16x32_bf16(ah[mi], bl[nj], acc[mi][nj], 0, 0, 0);
        acc[mi][nj] = __builtin_amdgcn_mfma_f32_16x16x32_bf16(al[mi], bh[nj], acc[mi][nj], 0, 0, 0);
      }
  }

  // epilogue — C/D layout: col = lane&15, row = (lane>>4)*4 + reg
  const int cl = lane & 15, qd = lane >> 4;
  const int colbase = bn + wc * SN;
  const int rowbase = bm + wr * SM;
  if (EPI == 1) {
    #pragma unroll
    for (int mi = 0; mi < T_M; ++mi) {
      int r0 = rowbase + mi * 16 + qd * 4;
      #pragma unroll
      for (int nj = 0; nj < T_N; ++nj) {
        int col = colbase + nj * 16 + cl;
        float bv = bias[col];
        #pragma unroll
        for (int rg = 0; rg < 4; ++rg)
          C[(size_t)(r0 + rg) * ldc + col] = acc[mi][nj][rg] + bv;
      }
    }
  } else if (EPI == 4) {
    #pragma unroll
    for (int mi = 0; mi < T_M; ++mi) {
      int m = rowbase + mi * 16 + qd * 4;
      int b = m >> 9, l = m & 511;
      #pragma unroll
      for (int nj = 0; nj < T_N; ++nj) {
        int col = colbase + nj * 16 + cl;
        float bv = bias[col];
        float4 v;
        v.x = softplusf(acc[mi][nj][0] + bv);
        v.y = softplusf(acc[mi][nj][1] + bv);
        v.z = softplusf(acc[mi][nj][2] + bv);
        v.w = softplusf(acc[mi][nj][3] + bv);
        *reinterpret_cast<float4*>(&C[((size_t)b * DIN + col) * LSEQ + l]) = v;
      }
    }
  } else if (EPI == 5) {
    if (bn < 1536) {
      #pragma unroll
      for (int mi = 0; mi < T_M; ++mi) {
        int r0 = rowbase + mi * 16 + qd * 4;
        #pragma unroll
        for (int nj = 0; nj < T_N; ++nj) {
          int col = colbase + nj * 16 + cl;
          #pragma unroll
          for (int rg = 0; rg < 4; ++rg)
            C[(size_t)(r0 + rg) * ldc + col] = acc[mi][nj][rg];
        }
      }
    } else {
      #pragma unroll
      for (int mi = 0; mi < T_M; ++mi) {
        int m = rowbase + mi * 16 + qd * 4;
        int b = m >> 9, l = m & 511;
        #pragma unroll
        for (int nj = 0; nj < T_N; ++nj) {
          int colz = colbase - 1536 + nj * 16 + cl;
          float4 v;
          v.x = acc[mi][nj][0]; v.y = acc[mi][nj][1];
          v.z = acc[mi][nj][2]; v.w = acc[mi][nj][3];
          *reinterpret_cast<float4*>(&C2[((size_t)b * DIN + colz) * LSEQ + l]) = v;
        }
      }
    }
  } else if (EPI == 6) {
    #pragma unroll
    for (int mi = 0; mi < T_M; ++mi) {
      int r0 = rowbase + mi * 16 + qd * 4;
      #pragma unroll
      for (int nj = 0; nj < T_N; ++nj) {
        int col = colbase + nj * 16 + cl;
        #pragma unroll
        for (int rg = 0; rg < 4; ++rg) {
          float v = acc[mi][nj][rg];
          C[(size_t)(r0 + rg) * 192 + col] = v;
          if (col < 64) {
            bf16 h, l;
            if (col < 48) bsplit(v, h, l);
            else { h = __float2bfloat16(0.f); l = h; }
            Oh[(size_t)(r0 + rg) * 64 + col] = h;
            Ol[(size_t)(r0 + rg) * 64 + col] = l;
          }
        }
      }
    }
  }
}

// ---------------------------------------------------------------------------
// Fused prep: modality hi/lo splits (blocks 0..36863) + all 4 weight
// transposes+splits (blocks 36864..37967).
__global__ __launch_bounds__(256) void prep_k(
    const float* __restrict__ s0, const float* __restrict__ s1,
    const float* __restrict__ s2, bf16* __restrict__ moddst,
    const float* __restrict__ pw, const float* __restrict__ ipw,
    const float* __restrict__ xpw, const float* __restrict__ dtw,
    bf16* pwTh, bf16* pwTl, bf16* ipTh, bf16* ipTl,
    bf16* xpTh, bf16* xpTl, bf16* dtTh, bf16* dtTl)
{
  __shared__ float T[64][65];
  const int tid = threadIdx.x;
  if (blockIdx.x < 36864) {
    const int per = 4096 * 768 / 256;
    int seg = blockIdx.x / per;
    int idx = (blockIdx.x - seg * per) * 256 + tid;
    const float* src = (seg == 0) ? s0 : (seg == 1) ? s1 : s2;
    bf16* hi = moddst + (size_t)seg * 2 * 4096 * 768;
    bf16* lo = hi + (size_t)4096 * 768;
    bf16 h, l; bsplit(src[idx], h, l);
    hi[idx] = h; lo[idx] = l;
    return;
  }
  const int id = blockIdx.x - 36864;
  const float* src; bf16 *hi, *lo; int P, Q, ld, Ppad, px, qx;
  if (id < 432)       { src = pw;  hi = pwTh; lo = pwTl; P = 2304; Q = 768;  ld = 768;  Ppad = 2304; px = id % 36;          qx = id / 36; }
  else if (id < 1008) { int i = id - 432;  src = ipw; hi = ipTh; lo = ipTl; P = 768;  Q = 3072; ld = 3072; Ppad = 768;  px = i % 12; qx = i / 12; }
  else if (id < 1080) { int i = id - 1008; src = xpw; hi = xpTh; lo = xpTl; P = 1536; Q = 176;  ld = 176;  Ppad = 1536; px = i % 24; qx = i / 24; }
  else                { int i = id - 1080; src = dtw; hi = dtTh; lo = dtTl; P = 48;   Q = 1536; ld = 1536; Ppad = 64;   px = 0;      qx = i; }
  const int p0 = px * 64, q0 = qx * 64;
  {
    int j = tid & 63, i0 = tid >> 6;
    for (int i = i0; i < 64; i += 4) {
      int p = p0 + i, q = q0 + j;
      T[i][j] = (p < P && q < Q) ? src[(size_t)p * ld + q] : 0.f;
    }
  }
  __syncthreads();
  {
    int ii = tid & 63, j0 = tid >> 6;
    for (int jj = j0; jj < 64; jj += 4) {
      bf16 h, l; bsplit(T[ii][jj], h, l);
      size_t o = (size_t)(q0 + jj) * Ppad + p0 + ii;
      hi[o] = h; lo[o] = l;
    }
  }
}

// ---------------------------------------------------------------------------
__device__ inline float block_sum256(float s, float* red) {
  #pragma unroll
  for (int o = 32; o > 0; o >>= 1) s += __shfl_xor(s, o, 64);
  int tid = threadIdx.x;
  __syncthreads();
  if ((tid & 63) == 0) red[tid >> 6] = s;
  __syncthreads();
  return red[0] + red[1] + red[2] + red[3];
}

__global__ __launch_bounds__(256) void ln2_k(
    const float* __restrict__ pre,
    const float* __restrict__ g1, const float* __restrict__ b1,
    const float* __restrict__ g2, const float* __restrict__ b2,
    float* __restrict__ fused, bf16* __restrict__ hAh, bf16* __restrict__ hAl)
{
  __shared__ float red[4];
  const int row = blockIdx.x;
  const int tid = threadIdx.x;
  const float* x = pre + (size_t)row * 768;
  float v0 = x[tid], v1 = x[tid + 256], v2 = x[tid + 512];

  float mu = block_sum256(v0 + v1 + v2, red) * (1.f / 768.f);
  float c0 = v0 - mu, c1 = v1 - mu, c2 = v2 - mu;
  float var = block_sum256(c0*c0 + c1*c1 + c2*c2, red) * (1.f / 768.f);
  float r = rsqrtf(var + 1e-5f);
  float f0 = c0 * r * g1[tid] + b1[tid];
  float f1 = c1 * r * g1[tid + 256] + b1[tid + 256];
  float f2 = c2 * r * g1[tid + 512] + b1[tid + 512];
  float* fo = fused + (size_t)row * 768;
  fo[tid] = f0; fo[tid + 256] = f1; fo[tid + 512] = f2;

  float mu2 = block_sum256(f0 + f1 + f2, red) * (1.f / 768.f);
  float d0 = f0 - mu2, d1 = f1 - mu2, d2 = f2 - mu2;
  float var2 = block_sum256(d0*d0 + d1*d1 + d2*d2, red) * (1.f / 768.f);
  float r2 = rsqrtf(var2 + 1e-5f);
  float h0 = d0 * r2 * g2[tid] + b2[tid];
  float h1 = d1 * r2 * g2[tid + 256] + b2[tid + 256];
  float h2 = d2 * r2 * g2[tid + 512] + b2[tid + 512];
  bf16 hh, hl;
  size_t o = (size_t)row * 768;
  bsplit(h0, hh, hl); hAh[o + tid] = hh; hAl[o + tid] = hl;
  bsplit(h1, hh, hl); hAh[o + tid + 256] = hh; hAl[o + tid + 256] = hl;
  bsplit(h2, hh, hl); hAh[o + tid + 512] = hh; hAl[o + tid + 512] = hl;
}

// Causal depthwise conv (K=4) + bias + silu.
// Outputs xct [B][DIN][L] fp32 (scan) AND xcA [row][DIN] bf16 hi/lo (x_proj A).
__global__ __launch_bounds__(256) void conv2x_k(
    const float* __restrict__ xbuf, const float* __restrict__ w,
    const float* __restrict__ cb, float* __restrict__ xct,
    bf16* __restrict__ xcAh, bf16* __restrict__ xcAl)
{
  __shared__ float Xs[67][65];
  __shared__ float Ys[64][65];
  const int tid = threadIdx.x;
  const int l0 = blockIdx.x * 64;
  const int d0 = blockIdx.y * 64;
  const int b  = blockIdx.z;
  for (int e = tid; e < 67 * 64; e += 256) {
    int r = e >> 6, dd = e & 63;
    int l = l0 - 3 + r;
    Xs[r][dd] = (l >= 0) ? xbuf[((size_t)b * 512 + l) * DIN + d0 + dd] : 0.f;
  }
  __syncthreads();
  {
    const int lane = tid & 63, grp = tid >> 6;
    #pragma unroll
    for (int i = 0; i < 16; ++i) {
      int dd = grp + i * 4;
      int d = d0 + dd;
      float acc = cb[d];
      #pragma unroll
      for (int k = 0; k < 4; ++k)
        acc = fmaf(Xs[lane + k][dd], w[d * 4 + k], acc);
      float v = acc / (1.f + __expf(-acc));
      xct[((size_t)b * DIN + d) * LSEQ + l0 + lane] = v;
      Ys[lane][dd] = v;
    }
  }
  __syncthreads();
  {
    const int dd = tid & 63, lg = tid >> 6;
    #pragma unroll
    for (int j = 0; j < 16; ++j) {
      int l = lg * 16 + j;
      bf16 h, lo; bsplit(Ys[l][dd], h, lo);
      size_t o = (size_t)(b * 512 + l0 + l) * DIN + d0 + dd;
      xcAh[o] = h; xcAl[o] = lo;
    }
  }
}

// Selective scan v6 (best measured: 187 us, occ 70%): 8 waves/block share one
// b and the BC stage; wave -> d; lane -> n. No per-step cross-lane reduction:
//   ysum = Sum_n a_n + D * Sum_t u[t]*sz[t],  a_n = Sum_t h[t,n]*C[t,n]*sz[t]
__global__ __launch_bounds__(512) void scan6_k(
    const float* __restrict__ delta_t, const float* __restrict__ xct,
    const float* __restrict__ dbl, const float* __restrict__ zt,
    const float* __restrict__ A_log, const float* __restrict__ Dv,
    float* __restrict__ ysbar)
{
  __shared__ float BC[64][128];      // [t][2n+{0,1}] = {B,C}  32 KB (block-shared)
  const int tid = threadIdx.x;
  const int lane = tid & 63;
  const int wv = tid >> 6;           // 8 waves
  const int bid = blockIdx.x;        // 1536 = 8 * 192
  const int b = bid / 192;
  const int d = (bid - b * 192) * 8 + wv;
  const float Ad2 = -__expf(A_log[d * 64 + lane]) * 1.442695041f;  // exp2 scale
  const float Dd = Dv[d];
  const size_t strm = ((size_t)b * DIN + d) * LSEQ;
  float h = 0.f;
  float a = 0.f;       // Sum_t h[t,n]*C[t,n]*sz[t]   (lane = n)
  float us = 0.f;      // Sum_t u[t]*sz[t]            (lane = t per chunk)

  for (int l0 = 0; l0 < LSEQ; l0 += 64) {
    __syncthreads();
    #pragma unroll
    for (int i = 0; i < 8; ++i) {
      int t = wv * 8 + i;
      const float* src = dbl + (size_t)(b * LSEQ + l0 + t) * 192;
      float2 v; v.x = src[48 + lane]; v.y = src[112 + lane];
      *reinterpret_cast<float2*>(&BC[t][lane * 2]) = v;
    }
    float dt_v = delta_t[strm + l0 + lane];
    float u_v  = xct[strm + l0 + lane];
    float z_v  = zt[strm + l0 + lane];
    float du_v = dt_v * u_v;
    float sz_v = z_v / (1.f + __expf(-z_v));
    us += u_v * sz_v;
    __syncthreads();

    #pragma unroll
    for (int t = 0; t < 64; ++t) {
      float sdt = readlane_f(dt_v, t);
      float sdu = readlane_f(du_v, t);
      float ssz = readlane_f(sz_v, t);
      float2 bc = *reinterpret_cast<const float2*>(&BC[t][lane * 2]);
      float e = exp2f(sdt * Ad2);
      h = fmaf(e, h, sdu * bc.x);
      a = fmaf(h, bc.y * ssz, a);
    }
  }
  float tot = readlane_f(dpp_wave_sum(a + Dd * us), 63);
  if (lane == 0) ysbar[b * 1536 + d] = tot;
}

// out[b][c] += slice contributions of (Sum_l fused + ysbar @ W)/512.
// Grid (3, 8, 24): z<8 -> l-slice of 64 rows of fused; z>=8 -> d-slice of 96
// for the ysbar dot. One atomicAdd per thread; out zeroed via hipMemsetAsync.
__global__ __launch_bounds__(256) void final2_k(
    const float* __restrict__ fused, const float* __restrict__ ysbar,
    const float* __restrict__ W, float* __restrict__ out)
{
  const int c = blockIdx.x * 256 + threadIdx.x;  // 0..767
  const int b = blockIdx.y;
  const int s = blockIdx.z;                      // 0..23
  float part = 0.f;
  if (s < 8) {
    const int l0 = s * 64;
    const float* fp = fused + (size_t)((b << 9) + l0) * 768 + c;
    #pragma unroll 4
    for (int l = 0; l < 64; ++l) part += fp[(size_t)l * 768];
  } else {
    const int d0 = (s - 8) * 96;
    #pragma unroll 4
    for (int i = 0; i < 96; ++i) {
      int d = d0 + i;
      part = fmaf(ysbar[b * 1536 + d], W[(size_t)d * 768 + c], part);
    }
  }
  atomicAdd(&out[b * 768 + c], part * (1.f / 512.f));
}

// ---------------------------------------------------------------------------
extern "C" void kernel_launch(void* const* d_in, const int* in_sizes, int n_in,
                              void* d_out, int out_size, void* d_ws, size_t ws_size,
                              hipStream_t stream)
{
  const float* text      = (const float*)d_in[0];
  const float* audio     = (const float*)d_in[1];
  const float* video     = (const float*)d_in[2];
  const float* proj_w    = (const float*)d_in[3];
  const float* proj_b    = (const float*)d_in[4];
  const float* proj_ln_g = (const float*)d_in[5];
  const float* proj_ln_b = (const float*)d_in[6];
  const float* blk_ln_g  = (const float*)d_in[7];
  const float* blk_ln_b  = (const float*)d_in[8];
  const float* in_proj_w = (const float*)d_in[9];
  const float* conv_w    = (const float*)d_in[10];
  const float* conv_b    = (const float*)d_in[11];
  const float* x_proj_w  = (const float*)d_in[12];
  const float* dt_proj_w = (const float*)d_in[13];
  const float* dt_proj_b = (const float*)d_in[14];
  const float* A_log     = (const float*)d_in[15];
  const float* Dv        = (const float*)d_in[16];
  const float* out_projw = (const float*)d_in[17];
  float* out = (float*)d_out;

  // ---- workspace arena ----
  char* p = (char*)d_ws;
  const size_t P768 = (size_t)4096 * 768 * 2;     // one bf16 [4096][768]
  char* S1 = p; p += 6 * P768;                    // modality splits -> hA -> xcA
  char* SW = p; p += 18087936;                    // weights
  char* S3 = p; p += (size_t)4096 * 768 * 4;      // pre
  char* S4 = p; p += (size_t)4096 * 768 * 4;      // fused
  char* S6 = p; p += (size_t)4096 * 1536 * 4;     // xbuf -> delta_t
  char* S7 = p; p += (size_t)4096 * 1536 * 4;     // zt
  char* S8 = p; p += (size_t)4096 * 1536 * 4;     // xct
  char* SD = p; p += (size_t)4096 * 64 * 4;       // dtA hi/lo
  char* S9 = p; p += (size_t)4096 * 192 * 4;      // dbl
  char* SY = p; p += 12288 * 4;                   // ysbar

  bf16* modspl = (bf16*)S1;
  bf16 *tAh = (bf16*)S1,              *tAl = (bf16*)(S1 + P768);
  bf16 *aAh = (bf16*)(S1 + 2 * P768), *aAl = (bf16*)(S1 + 3 * P768);
  bf16 *vAh = (bf16*)(S1 + 4 * P768), *vAl = (bf16*)(S1 + 5 * P768);
  bf16 *hAh = (bf16*)S1,              *hAl = (bf16*)(S1 + P768);
  bf16 *xcAh = (bf16*)S1,             *xcAl = (bf16*)(S1 + (size_t)4096 * 1536 * 2);
  bf16 *pwTh = (bf16*)SW,                    *pwTl = pwTh + (size_t)768 * 2304;
  bf16 *ipTh = pwTl + (size_t)768 * 2304,    *ipTl = ipTh + (size_t)3072 * 768;
  bf16 *xpTh = ipTl + (size_t)3072 * 768,    *xpTl = xpTh + (size_t)192 * 1536;
  bf16 *dtTh = xpTl + (size_t)192 * 1536,    *dtTl = dtTh + (size_t)1536 * 64;
  float* pre     = (float*)S3;
  float* fused   = (float*)S4;
  float* xbuf    = (float*)S6;  float* delta_t = (float*)S6;
  float* zt      = (float*)S7;
  float* xct     = (float*)S8;
  bf16 *dtAh = (bf16*)SD, *dtAl = (bf16*)(SD + (size_t)4096 * 64 * 2);
  float* dbl     = (float*)S9;
  float* ysbar   = (float*)SY;

  // 1) all prep (modality splits + weight transposes) in one launch
  prep_k<<<37968, 256, 0, stream>>>(text, audio, video, modspl,
                                    proj_w, in_proj_w, x_proj_w, dt_proj_w,
                                    pwTh, pwTl, ipTh, ipTl, xpTh, xpTl, dtTh, dtTl);
  // 2) pre = concat @ proj_w + proj_b   (m97-class 128x128 tile)
  mgemm<128, 128, 2, 2, 1, 1><<<dim3(32, 6), 256, 0, stream>>>(
      tAh, tAl, aAh, aAl, vAh, vAl, pwTh, pwTl, proj_b,
      pre, nullptr, nullptr, nullptr, 2304, 768, 768);
  // 3) fused = LN1(pre); hA = split(LN2(fused))
  ln2_k<<<4096, 256, 0, stream>>>(pre, proj_ln_g, proj_ln_b, blk_ln_g, blk_ln_b, fused, hAh, hAl);
  // 4) [x|z] = h @ in_proj_w: x -> xbuf [4096][1536], z -> zt [B][DIN][L]
  mgemm<128, 128, 2, 2, 0, 5><<<dim3(32, 24), 256, 0, stream>>>(
      hAh, hAl, nullptr, nullptr, nullptr, nullptr, ipTh, ipTl, nullptr,
      xbuf, zt, nullptr, nullptr, 768, 768, 1536);
  // 5) xct = silu(dwconv(x)+cb) transposed; xcA = split(xct) row-major
  conv2x_k<<<dim3(8, 24, 8), 256, 0, stream>>>(xbuf, conv_w, conv_b, xct, xcAh, xcAl);
  // 6) dbl = xconv @ x_proj_w [4096][192] fp32 + dtA hi/lo (cols<48, pad 64)
  mgemm<64, 64, 4, 2, 0, 6><<<dim3(64, 3), 512, 0, stream>>>(
      xcAh, xcAl, nullptr, nullptr, nullptr, nullptr, xpTh, xpTl, nullptr,
      dbl, nullptr, dtAh, dtAl, 1536, 1536, 192);
  // 7) delta_t = softplus(dt @ dt_proj_w + b) transposed [B][DIN][L]
  mgemm<128, 128, 2, 2, 0, 4><<<dim3(32, 12), 256, 0, stream>>>(
      dtAh, dtAl, nullptr, nullptr, nullptr, nullptr, dtTh, dtTl, dt_proj_b,
      delta_t, nullptr, nullptr, nullptr, 64, 64, 0);
  // 8) selective scan -> ysbar[b][d] = sum_l y
  scan6_k<<<1536, 512, 0, stream>>>(delta_t, xct, dbl, zt, A_log, Dv, ysbar);
  // 9) out = (sum_l fused + ysbar @ out_proj_w) / 512, sliced + atomics
  hipMemsetAsync(d_out, 0, (size_t)out_size * sizeof(float), stream);
  final2_k<<<dim3(3, 8, 24), 256, 0, stream>>>(fused, ysbar, out_projw, out);
}